// Round 5
// baseline (963.465 us; speedup 1.0000x reference)
//
#include <hip/hip_runtime.h>

#define MNODES 50000
#define M_PAD  50048          // 391 * 128
#define NEDGES 800000
#define DIN    128
#define DD     256
#define D2     512
#define NLAYERS 3
#define BN_EPS 1e-5f

typedef unsigned short ushort_t;
typedef __bf16 v8bf __attribute__((ext_vector_type(8)));
typedef float  v4f  __attribute__((ext_vector_type(4)));

__device__ __forceinline__ float bf2f(ushort_t u) {
    unsigned x = ((unsigned)u) << 16;
    return __uint_as_float(x);
}
__device__ __forceinline__ ushort_t f2bf(float f) {
    unsigned u = __float_as_uint(f);
    u += 0x7FFF + ((u >> 16) & 1);   // RNE
    return (ushort_t)(u >> 16);
}
// barrier that drains LDS ops but leaves global loads (vmcnt) in flight
__device__ __forceinline__ void softbarrier() {
    asm volatile("s_waitcnt lgkmcnt(0)\n\ts_barrier" ::: "memory");
}

// ---------------- fused prep ----------------
#define R0 (M_PAD * DIN)                       // 6406144
#define RW (DIN * DD + 2 * NLAYERS * DD * D2)  // 819200
__global__ void k_prep_all(const float* __restrict__ pre, ushort_t* __restrict__ preb,
                           const float* __restrict__ W0, const float* __restrict__ W1,
                           const float* __restrict__ W2,
                           ushort_t* __restrict__ W0T, ushort_t* __restrict__ W1T,
                           ushort_t* __restrict__ W2T,
                           float* __restrict__ caf, float* __restrict__ ccf,
                           float* __restrict__ sums1, float* __restrict__ sumsF,
                           int* __restrict__ deg) {
    int i = blockIdx.x * blockDim.x + threadIdx.x;
    if (i < R0) {
        int row = i >> 7;
        preb[i] = f2bf(row < MNODES ? pre[i] : 0.f);
        return;
    }
    int j = i - R0;
    if (j < RW) {
        if (j < DIN * DD) {
            int n = j >> 7, k = j & 127;
            W0T[j] = f2bf(W0[k * DD + n]);
        } else if (j < DIN * DD + NLAYERS * DD * D2) {
            int j2 = j - DIN * DD;
            int l = j2 >> 17, off = j2 & 131071;
            int n = off >> 8, k = off & 255;      // K=256, N=512
            W1T[(size_t)l * 131072 + off] = f2bf(W1[(size_t)l * 131072 + k * D2 + n]);
        } else {
            int j2 = j - DIN * DD - NLAYERS * DD * D2;
            int l = j2 >> 17, off = j2 & 131071;
            int n = off >> 9, k = off & 511;      // K=512, N=256
            W2T[(size_t)l * 131072 + off] = f2bf(W2[(size_t)l * 131072 + k * DD + n]);
        }
        return;
    }
    j -= RW;
    if (j < 256) { caf[j] = 1.f; ccf[j] = 0.f; return; }
    j -= 256;
    if (j < 1024) { sums1[j] = 0.f; return; }
    j -= 1024;
    if (j < 512) { sumsF[j] = 0.f; return; }
    j -= 512;
    if (j < MNODES) deg[j] = 0;
}

// ---------------- CSR build ----------------
__global__ void k_hist(const int* __restrict__ ei, int* __restrict__ deg) {
    int e = blockIdx.x * blockDim.x + threadIdx.x;
    if (e < NEDGES) atomicAdd(&deg[ei[e * 2 + 1]], 1);
}
__global__ void k_scan1(const int* __restrict__ deg, int* __restrict__ rowptr,
                        int* __restrict__ bsum, int n) {
    __shared__ int tmp[256];
    int tid = threadIdx.x;
    int i = blockIdx.x * 256 + tid;
    int v = (i < n) ? deg[i] : 0;
    tmp[tid] = v;
    __syncthreads();
    #pragma unroll
    for (int off = 1; off < 256; off <<= 1) {
        int t = (tid >= off) ? tmp[tid - off] : 0;
        __syncthreads();
        tmp[tid] += t;
        __syncthreads();
    }
    if (i < n) rowptr[i + 1] = tmp[tid];
    if (tid == 255) bsum[blockIdx.x] = tmp[255];
}
__global__ __launch_bounds__(256)
void k_scan2(int* __restrict__ bsum, int nb) {
    __shared__ int tmp[256];
    int tid = threadIdx.x;
    int v = (tid < nb) ? bsum[tid] : 0;
    tmp[tid] = v;
    __syncthreads();
    #pragma unroll
    for (int off = 1; off < 256; off <<= 1) {
        int t = (tid >= off) ? tmp[tid - off] : 0;
        __syncthreads();
        tmp[tid] += t;
        __syncthreads();
    }
    if (tid < nb) bsum[tid] = tmp[tid] - v;
}
__global__ void k_scan3(const int* __restrict__ deg, const int* __restrict__ bsum,
                        int* __restrict__ rowptr, int* __restrict__ cursor, int n) {
    int i = blockIdx.x * 256 + threadIdx.x;
    if (i == 0) rowptr[0] = 0;
    if (i < n) {
        int incl = rowptr[i + 1] + bsum[i >> 8];
        rowptr[i + 1] = incl;
        cursor[i] = incl - deg[i];
    }
}
__global__ void k_fill(const int* __restrict__ ei, int* __restrict__ cursor,
                       int* __restrict__ col) {
    int e = blockIdx.x * blockDim.x + threadIdx.x;
    if (e < NEDGES) {
        int pos = atomicAdd(&cursor[ei[e * 2 + 1]], 1);
        col[pos] = ei[e * 2];
    }
}

// ---------------- gather ----------------
__global__ void k_gather(const int* __restrict__ rowptr, const int* __restrict__ col,
                         const ushort_t* __restrict__ x, const float* __restrict__ ca,
                         const float* __restrict__ cc, ushort_t* __restrict__ out) {
    int node = blockIdx.x * 4 + (threadIdx.x >> 6);
    int lane = threadIdx.x & 63;
    if (node >= MNODES) return;
    const ushort4* xp = (const ushort4*)x;
    ushort4 v = xp[(size_t)node * 64 + lane];
    float a0 = bf2f(v.x), a1 = bf2f(v.y), a2 = bf2f(v.z), a3 = bf2f(v.w);
    int s = rowptr[node], e = rowptr[node + 1];
    int i = s;
    for (; i + 3 < e; i += 4) {
        ushort4 u0 = xp[(size_t)col[i]     * 64 + lane];
        ushort4 u1 = xp[(size_t)col[i + 1] * 64 + lane];
        ushort4 u2 = xp[(size_t)col[i + 2] * 64 + lane];
        ushort4 u3 = xp[(size_t)col[i + 3] * 64 + lane];
        a0 += bf2f(u0.x) + bf2f(u1.x) + bf2f(u2.x) + bf2f(u3.x);
        a1 += bf2f(u0.y) + bf2f(u1.y) + bf2f(u2.y) + bf2f(u3.y);
        a2 += bf2f(u0.z) + bf2f(u1.z) + bf2f(u2.z) + bf2f(u3.z);
        a3 += bf2f(u0.w) + bf2f(u1.w) + bf2f(u2.w) + bf2f(u3.w);
    }
    for (; i < e; i++) {
        ushort4 u = xp[(size_t)col[i] * 64 + lane];
        a0 += bf2f(u.x); a1 += bf2f(u.y); a2 += bf2f(u.z); a3 += bf2f(u.w);
    }
    int c = lane * 4;
    float dn = (float)(e - s) + 1.0f;
    ushort4 o;
    o.x = f2bf(ca[c + 0] * a0 + dn * cc[c + 0]);
    o.y = f2bf(ca[c + 1] * a1 + dn * cc[c + 1]);
    o.z = f2bf(ca[c + 2] * a2 + dn * cc[c + 2]);
    o.w = f2bf(ca[c + 3] * a3 + dn * cc[c + 3]);
    ((ushort4*)out)[(size_t)node * 64 + lane] = o;
}

// ---------------- BN coeffs (re-zeros stats) ----------------
__global__ void k_coeffs(float* __restrict__ sums, float* __restrict__ sumsq,
                         const float* __restrict__ g, const float* __restrict__ beta,
                         float* __restrict__ ca, float* __restrict__ cc, int n) {
    int c = blockIdx.x * blockDim.x + threadIdx.x;
    if (c >= n) return;
    float mean = sums[c] * (1.0f / MNODES);
    float var  = sumsq[c] * (1.0f / MNODES) - mean * mean;
    float a    = g[c] * rsqrtf(var + BN_EPS);
    ca[c] = a;
    cc[c] = beta[c] - a * mean;
    sums[c] = 0.f;
    sumsq[c] = 0.f;
}

// ---------------- final: d_out = ca*h + cc (fp32) ----------------
__global__ void k_apply_out(const ushort_t* __restrict__ h, const float* __restrict__ ca,
                            const float* __restrict__ cc, float* __restrict__ out) {
    int i = blockIdx.x * blockDim.x + threadIdx.x;
    if (i >= MNODES * 64) return;
    int c = (i & 63) * 4;
    ushort4 v = ((const ushort4*)h)[i];
    float4 o;
    o.x = ca[c + 0] * bf2f(v.x) + cc[c + 0];
    o.y = ca[c + 1] * bf2f(v.y) + cc[c + 1];
    o.z = ca[c + 2] * bf2f(v.z) + cc[c + 2];
    o.w = ca[c + 3] * bf2f(v.w) + cc[c + 3];
    ((float4*)out)[i] = o;
}

// PRE transform: relu(ca*x+cc) on 8 packed bf16, coeffs from LDS at k-base kb
__device__ __forceinline__ uint4 bn_relu_pack(uint4 v, const float* pca,
                                              const float* pcc, int kb) {
    uint4 o;
    #pragma unroll
    for (int d = 0; d < 4; d++) {
        unsigned x = ((const unsigned*)&v)[d];
        float lo = bf2f((ushort_t)(x & 0xFFFF));
        float hi = bf2f((ushort_t)(x >> 16));
        lo = fmaxf(pca[kb + 2 * d] * lo + pcc[kb + 2 * d], 0.f);
        hi = fmaxf(pca[kb + 2 * d + 1] * hi + pcc[kb + 2 * d + 1], 0.f);
        ((unsigned*)&o)[d] = (unsigned)f2bf(lo) | ((unsigned)f2bf(hi) << 16);
    }
    return o;
}

// ---------------- pipelined bf16 MFMA GEMM, 128x128 tile, BK=64, LDS dbuf ----
// out[M,N](bf16) = preT(A)[M_PAD,K] @ WT[N,K]^T + bias[N]
//   PRE: a = relu(p_ca[k]*a + p_cc[k]) applied during A staging (K<=512)
//   RES: += r_ca[col]*resid[row,col] + r_cc[col]
//   DO_STATS: column sums/sumsq of fp32 result via atomics
template<int DO_STATS, int RES, int PRE>
__global__ __launch_bounds__(256)
void k_gemm_bf(const ushort_t* __restrict__ A, const ushort_t* __restrict__ WT,
               const float* __restrict__ bias,
               const ushort_t* resid, const float* __restrict__ r_ca,
               const float* __restrict__ r_cc,
               const float* __restrict__ p_ca, const float* __restrict__ p_cc,
               ushort_t* out, float* __restrict__ sums, float* __restrict__ sumsq,
               int M, int K, int N) {
    __shared__ ushort_t As[2][128 * 64];   // swizzled: LDS slot s of row r holds chunk s^(r&7)
    __shared__ ushort_t Bs[2][128 * 64];
    __shared__ float spca[PRE ? 512 : 1];
    __shared__ float spcc[PRE ? 512 : 1];

    const int tid = threadIdx.x;
    const int w = tid >> 6, lane = tid & 63;
    const int wm = w >> 1, wn = w & 1;
    const int quad = lane >> 4, l15 = lane & 15;
    const int m0 = blockIdx.y * 128, n0 = blockIdx.x * 128;

    // staging geometry (same for A and B): 4 row-blocks per thread
    const int r_in = lane >> 3;           // row within 8-row block
    const int s_slot = lane & 7;          // LDS chunk slot
    const int cg = s_slot ^ r_in;         // global chunk held in this slot
    const ushort_t* aA[4];
    const ushort_t* aB[4];
    int ldsoff[4];
    #pragma unroll
    for (int i = 0; i < 4; i++) {
        int rblk = i * 4 + w;
        int r = rblk * 8 + r_in;
        aA[i] = A  + (size_t)(m0 + r) * K + cg * 8;
        aB[i] = WT + (size_t)(n0 + r) * K + cg * 8;
        ldsoff[i] = rblk * 512 + r_in * 64 + s_slot * 8;
    }

    v4f acc[4][4];
    #pragma unroll
    for (int i = 0; i < 4; i++)
        #pragma unroll
        for (int j = 0; j < 4; j++)
            acc[i][j] = (v4f){0.f, 0.f, 0.f, 0.f};

    const int nk = K >> 6;
    uint4 ar[4], br[4];

    // prologue: stage PRE coeffs; load+write tile 0; load tile 1
    if (PRE) {
        for (int i = tid; i < K; i += 256) { spca[i] = p_ca[i]; spcc[i] = p_cc[i]; }
    }
    #pragma unroll
    for (int i = 0; i < 4; i++) { ar[i] = *(const uint4*)aA[i]; br[i] = *(const uint4*)aB[i]; }
    if (PRE) __syncthreads();   // coeffs visible before transform
    #pragma unroll
    for (int i = 0; i < 4; i++) {
        uint4 va = PRE ? bn_relu_pack(ar[i], spca, spcc, cg * 8) : ar[i];
        *(uint4*)&As[0][ldsoff[i]] = va;
        *(uint4*)&Bs[0][ldsoff[i]] = br[i];
    }
    if (nk > 1) {
        #pragma unroll
        for (int i = 0; i < 4; i++) {
            ar[i] = *(const uint4*)(aA[i] + 64);
            br[i] = *(const uint4*)(aB[i] + 64);
        }
    }
    softbarrier();

    for (int t = 0; t < nk; t++) {
        if (t + 1 < nk) {
            // write tile t+1 (in regs) into the other buffer — prior readers
            // of that buffer finished at the last softbarrier
            int buf = (t + 1) & 1;
            int kw = (t + 1) * 64;
            #pragma unroll
            for (int i = 0; i < 4; i++) {
                uint4 va = PRE ? bn_relu_pack(ar[i], spca, spcc, kw + cg * 8) : ar[i];
                *(uint4*)&As[buf][ldsoff[i]] = va;
                *(uint4*)&Bs[buf][ldsoff[i]] = br[i];
            }
            if (t + 2 < nk) {       // issue loads for tile t+2; stay in flight across barrier
                int kl = (t + 2) * 64;
                #pragma unroll
                for (int i = 0; i < 4; i++) {
                    ar[i] = *(const uint4*)(aA[i] + kl);
                    br[i] = *(const uint4*)(aB[i] + kl);
                }
            }
        }
        // compute on buffer t&1
        const ushort_t* Ab = As[t & 1];
        const ushort_t* Bb = Bs[t & 1];
        #pragma unroll
        for (int ks = 0; ks < 2; ks++) {
            v8bf af[4], bfr[4];
            int cl = (ks * 4 + quad) ^ (l15 & 7);
            #pragma unroll
            for (int tt = 0; tt < 4; tt++) {
                int m_l = wm * 64 + tt * 16 + l15;
                af[tt] = *(const v8bf*)&Ab[m_l * 64 + cl * 8];
                int n_l = wn * 64 + tt * 16 + l15;
                bfr[tt] = *(const v8bf*)&Bb[n_l * 64 + cl * 8];
            }
            #pragma unroll
            for (int mt = 0; mt < 4; mt++)
                #pragma unroll
                for (int nt = 0; nt < 4; nt++)
                    acc[mt][nt] = __builtin_amdgcn_mfma_f32_16x16x32_bf16(
                        af[mt], bfr[nt], acc[mt][nt], 0, 0, 0);
        }
        softbarrier();
    }

    // epilogue
    const int mlim = M - m0;
    float s_sum[4] = {0.f, 0.f, 0.f, 0.f}, s_sq[4] = {0.f, 0.f, 0.f, 0.f};
    #pragma unroll
    for (int nt = 0; nt < 4; nt++) {
        int colg = n0 + wn * 64 + nt * 16 + l15;
        float bia = bias[colg];
        float rca = 0.f, rcc = 0.f;
        if (RES) { rca = r_ca[colg]; rcc = r_cc[colg]; }
        #pragma unroll
        for (int mt = 0; mt < 4; mt++) {
            int rbase = wm * 64 + mt * 16 + quad * 4;
            #pragma unroll
            for (int r = 0; r < 4; r++) {
                int rl = rbase + r;
                if (rl < mlim) {
                    size_t idx = (size_t)(m0 + rl) * N + colg;
                    float v = acc[mt][nt][r] + bia;
                    if (RES) v += rca * bf2f(resid[idx]) + rcc;
                    out[idx] = f2bf(v);
                    if (DO_STATS) { s_sum[nt] += v; s_sq[nt] += v * v; }
                }
            }
        }
    }
    if (DO_STATS) {
        #pragma unroll
        for (int nt = 0; nt < 4; nt++) {
            float s = s_sum[nt], q = s_sq[nt];
            s += __shfl_xor(s, 16); q += __shfl_xor(q, 16);
            s += __shfl_xor(s, 32); q += __shfl_xor(q, 32);
            if (quad == 0) {
                int colg = n0 + wn * 64 + nt * 16 + l15;
                atomicAdd(&sums[colg], s);
                atomicAdd(&sumsq[colg], q);
            }
        }
    }
}

extern "C" void kernel_launch(void* const* d_in, const int* in_sizes, int n_in,
                              void* d_out, int out_size, void* d_ws, size_t ws_size,
                              hipStream_t stream) {
    const float* pre   = (const float*)d_in[0];
    const int*   ei    = (const int*)d_in[1];
    const float* W0    = (const float*)d_in[2];
    const float* b0    = (const float*)d_in[3];
    const float* W1    = (const float*)d_in[4];
    const float* b1    = (const float*)d_in[5];
    const float* g1    = (const float*)d_in[6];
    const float* beta1 = (const float*)d_in[7];
    const float* W2    = (const float*)d_in[8];
    const float* b2    = (const float*)d_in[9];
    const float* gf    = (const float*)d_in[10];
    const float* betaf = (const float*)d_in[11];

    char* p = (char*)d_ws;
    ushort_t* preb = (ushort_t*)p; p += (size_t)M_PAD * DIN * 2;
    ushort_t* ACT1 = (ushort_t*)p; p += (size_t)M_PAD * DD * 2;
    ushort_t* ACT2 = (ushort_t*)p; p += (size_t)M_PAD * DD * 2;
    ushort_t* H1   = (ushort_t*)p; p += (size_t)M_PAD * D2 * 2;
    ushort_t* W0T  = (ushort_t*)p; p += (size_t)DIN * DD * 2;
    ushort_t* W1T  = (ushort_t*)p; p += (size_t)NLAYERS * DD * D2 * 2;
    ushort_t* W2T  = (ushort_t*)p; p += (size_t)NLAYERS * D2 * DD * 2;
    float* sums1  = (float*)p; p += D2 * 4;
    float* sumsq1 = (float*)p; p += D2 * 4;
    float* ca1    = (float*)p; p += D2 * 4;
    float* cc1    = (float*)p; p += D2 * 4;
    float* sumsF  = (float*)p; p += DD * 4;
    float* sumsqF = (float*)p; p += DD * 4;
    float* caf    = (float*)p; p += DD * 4;
    float* ccf    = (float*)p; p += DD * 4;
    int* deg    = (int*)p; p += (size_t)MNODES * 4;
    int* rowptr = (int*)p; p += (size_t)(MNODES + 1) * 4;
    int* cursor = (int*)p; p += (size_t)MNODES * 4;
    int* colx   = (int*)p; p += (size_t)NEDGES * 4;
    int* bsum   = (int*)p; p += 256 * 4;

    dim3 blk(256);
    const int mb = (MNODES + 127) / 128;        // 391
    const int nsb = (MNODES + 255) / 256;       // 196

    const int prep_total = R0 + RW + 256 + 1024 + 512 + MNODES;
    k_prep_all<<<(prep_total + 255) / 256, blk, 0, stream>>>(
        pre, preb, W0, W1, W2, W0T, W1T, W2T, caf, ccf, sums1, sumsF, deg);

    k_hist<<<(NEDGES + 255) / 256, blk, 0, stream>>>(ei, deg);
    k_scan1<<<nsb, blk, 0, stream>>>(deg, rowptr, bsum, MNODES);
    k_scan2<<<1, blk, 0, stream>>>(bsum, nsb);
    k_scan3<<<nsb, blk, 0, stream>>>(deg, bsum, rowptr, cursor, MNODES);
    k_fill<<<(NEDGES + 255) / 256, blk, 0, stream>>>(ei, cursor, colx);

    // X0 = pre @ W0 + b0  -> ACT2
    k_gemm_bf<0, 0, 0><<<dim3(DD / 128, mb), blk, 0, stream>>>(
        preb, W0T, b0, nullptr, nullptr, nullptr, nullptr, nullptr,
        ACT2, nullptr, nullptr, MNODES, DIN, DD);

    for (int l = 0; l < NLAYERS; l++) {
        // ACT1 = caf*(ACT2[n] + sum ACT2[src]) + (deg+1)*ccf
        k_gather<<<(MNODES + 3) / 4, blk, 0, stream>>>(rowptr, colx, ACT2, caf, ccf, ACT1);

        // H1 = ACT1 @ W1 + b1 (raw), fused column stats
        k_gemm_bf<1, 0, 0><<<dim3(D2 / 128, mb), blk, 0, stream>>>(
            ACT1, W1T + (size_t)l * DD * D2, b1 + (size_t)l * D2,
            nullptr, nullptr, nullptr, nullptr, nullptr,
            H1, sums1, sumsq1, MNODES, DD, D2);
        k_coeffs<<<2, blk, 0, stream>>>(sums1, sumsq1, g1 + (size_t)l * D2,
                                        beta1 + (size_t)l * D2, ca1, cc1, D2);

        // ACT2 = relu(bn1(H1)) @ W2 + b2 + bn_prev(ACT2)  (PRE fused; in place)
        k_gemm_bf<1, 1, 1><<<dim3(DD / 128, mb), blk, 0, stream>>>(
            H1, W2T + (size_t)l * D2 * DD, b2 + (size_t)l * DD,
            ACT2, caf, ccf, ca1, cc1,
            ACT2, sumsF, sumsqF, MNODES, D2, DD);
        k_coeffs<<<1, blk, 0, stream>>>(sumsF, sumsqF, gf + (size_t)l * DD,
                                        betaf + (size_t)l * DD, caf, ccf, DD);
    }

    // d_out = caf*ACT2 + ccf  (fp32)
    k_apply_out<<<(MNODES * 64 + 255) / 256, blk, 0, stream>>>(ACT2, caf, ccf, (float*)d_out);
}

// Round 6
// 807.257 us; speedup vs baseline: 1.1935x; 1.1935x over previous
//
#include <hip/hip_runtime.h>

#define MNODES 50000
#define M_PAD  50048          // 391 * 128
#define NEDGES 800000
#define DIN    128
#define DD     256
#define D2     512
#define NLAYERS 3
#define BN_EPS 1e-5f

typedef unsigned short ushort_t;
typedef __bf16 v8bf __attribute__((ext_vector_type(8)));
typedef float  v4f  __attribute__((ext_vector_type(4)));

#define GLOBAL_AS __attribute__((address_space(1)))
#define LDS_AS    __attribute__((address_space(3)))

__device__ __forceinline__ float bf2f(ushort_t u) {
    unsigned x = ((unsigned)u) << 16;
    return __uint_as_float(x);
}
__device__ __forceinline__ ushort_t f2bf(float f) {
    unsigned u = __float_as_uint(f);
    u += 0x7FFF + ((u >> 16) & 1);   // RNE
    return (ushort_t)(u >> 16);
}
__device__ __forceinline__ void async16(const ushort_t* g, ushort_t* l) {
    __builtin_amdgcn_global_load_lds((const GLOBAL_AS unsigned int*)g,
                                     (LDS_AS unsigned int*)l, 16, 0, 0);
}
// raw barrier: no vmcnt drain (DMA loads stay in flight); compiler has already
// waited lgkmcnt for MFMA operand consumption before we get here
#define BARRIER() asm volatile("s_barrier" ::: "memory")
#define VMWAIT4() asm volatile("s_waitcnt vmcnt(4)" ::: "memory")
#define VMWAIT0() asm volatile("s_waitcnt vmcnt(0)" ::: "memory")

// ---------------- fused prep ----------------
#define R0 (M_PAD * DIN)                       // 6406144
#define RW (DIN * DD + 2 * NLAYERS * DD * D2)  // 819200
__global__ void k_prep_all(const float* __restrict__ pre, ushort_t* __restrict__ preb,
                           const float* __restrict__ W0, const float* __restrict__ W1,
                           const float* __restrict__ W2,
                           ushort_t* __restrict__ W0T, ushort_t* __restrict__ W1T,
                           ushort_t* __restrict__ W2T,
                           float* __restrict__ caf, float* __restrict__ ccf,
                           float* __restrict__ sums1, float* __restrict__ sumsF,
                           int* __restrict__ deg) {
    int i = blockIdx.x * blockDim.x + threadIdx.x;
    if (i < R0) {
        int row = i >> 7;
        preb[i] = f2bf(row < MNODES ? pre[i] : 0.f);
        return;
    }
    int j = i - R0;
    if (j < RW) {
        if (j < DIN * DD) {
            int n = j >> 7, k = j & 127;
            W0T[j] = f2bf(W0[k * DD + n]);
        } else if (j < DIN * DD + NLAYERS * DD * D2) {
            int j2 = j - DIN * DD;
            int l = j2 >> 17, off = j2 & 131071;
            int n = off >> 8, k = off & 255;      // K=256, N=512
            W1T[(size_t)l * 131072 + off] = f2bf(W1[(size_t)l * 131072 + k * D2 + n]);
        } else {
            int j2 = j - DIN * DD - NLAYERS * DD * D2;
            int l = j2 >> 17, off = j2 & 131071;
            int n = off >> 9, k = off & 511;      // K=512, N=256
            W2T[(size_t)l * 131072 + off] = f2bf(W2[(size_t)l * 131072 + k * DD + n]);
        }
        return;
    }
    j -= RW;
    if (j < 256) { caf[j] = 1.f; ccf[j] = 0.f; return; }
    j -= 256;
    if (j < 1024) { sums1[j] = 0.f; return; }
    j -= 1024;
    if (j < 512) { sumsF[j] = 0.f; return; }
    j -= 512;
    if (j < MNODES) deg[j] = 0;
}

// ---------------- CSR build ----------------
__global__ void k_hist(const int* __restrict__ ei, int* __restrict__ deg) {
    int e = blockIdx.x * blockDim.x + threadIdx.x;
    if (e < NEDGES) atomicAdd(&deg[ei[e * 2 + 1]], 1);
}
__global__ void k_scan1(const int* __restrict__ deg, int* __restrict__ rowptr,
                        int* __restrict__ bsum, int n) {
    __shared__ int tmp[256];
    int tid = threadIdx.x;
    int i = blockIdx.x * 256 + tid;
    int v = (i < n) ? deg[i] : 0;
    tmp[tid] = v;
    __syncthreads();
    #pragma unroll
    for (int off = 1; off < 256; off <<= 1) {
        int t = (tid >= off) ? tmp[tid - off] : 0;
        __syncthreads();
        tmp[tid] += t;
        __syncthreads();
    }
    if (i < n) rowptr[i + 1] = tmp[tid];
    if (tid == 255) bsum[blockIdx.x] = tmp[255];
}
__global__ __launch_bounds__(256)
void k_scan2(int* __restrict__ bsum, int nb) {
    __shared__ int tmp[256];
    int tid = threadIdx.x;
    int v = (tid < nb) ? bsum[tid] : 0;
    tmp[tid] = v;
    __syncthreads();
    #pragma unroll
    for (int off = 1; off < 256; off <<= 1) {
        int t = (tid >= off) ? tmp[tid - off] : 0;
        __syncthreads();
        tmp[tid] += t;
        __syncthreads();
    }
    if (tid < nb) bsum[tid] = tmp[tid] - v;
}
__global__ void k_scan3(const int* __restrict__ deg, const int* __restrict__ bsum,
                        int* __restrict__ rowptr, int* __restrict__ cursor, int n) {
    int i = blockIdx.x * 256 + threadIdx.x;
    if (i == 0) rowptr[0] = 0;
    if (i < n) {
        int incl = rowptr[i + 1] + bsum[i >> 8];
        rowptr[i + 1] = incl;
        cursor[i] = incl - deg[i];
    }
}
__global__ void k_fill(const int* __restrict__ ei, int* __restrict__ cursor,
                       int* __restrict__ col) {
    int e = blockIdx.x * blockDim.x + threadIdx.x;
    if (e < NEDGES) {
        int pos = atomicAdd(&cursor[ei[e * 2 + 1]], 1);
        col[pos] = ei[e * 2];
    }
}

// ---------------- gather: out = ca*(x[n] + sum x[src]) + (deg+1)*cc ----------
__global__ void k_gather(const int* __restrict__ rowptr, const int* __restrict__ col,
                         const ushort_t* __restrict__ x, const float* __restrict__ ca,
                         const float* __restrict__ cc, ushort_t* __restrict__ out) {
    int node = blockIdx.x * 4 + (threadIdx.x >> 6);
    int lane = threadIdx.x & 63;
    if (node >= MNODES) return;
    const ushort4* xp = (const ushort4*)x;
    ushort4 v = xp[(size_t)node * 64 + lane];
    float a0 = bf2f(v.x), a1 = bf2f(v.y), a2 = bf2f(v.z), a3 = bf2f(v.w);
    int s = rowptr[node], e = rowptr[node + 1];
    int i = s;
    for (; i + 7 < e; i += 8) {       // 8 loads in flight
        ushort4 u[8];
        #pragma unroll
        for (int j = 0; j < 8; j++) u[j] = xp[(size_t)col[i + j] * 64 + lane];
        #pragma unroll
        for (int j = 0; j < 8; j++) {
            a0 += bf2f(u[j].x); a1 += bf2f(u[j].y);
            a2 += bf2f(u[j].z); a3 += bf2f(u[j].w);
        }
    }
    for (; i < e; i++) {
        ushort4 u = xp[(size_t)col[i] * 64 + lane];
        a0 += bf2f(u.x); a1 += bf2f(u.y); a2 += bf2f(u.z); a3 += bf2f(u.w);
    }
    int c = lane * 4;
    float dn = (float)(e - s) + 1.0f;
    ushort4 o;
    o.x = f2bf(ca[c + 0] * a0 + dn * cc[c + 0]);
    o.y = f2bf(ca[c + 1] * a1 + dn * cc[c + 1]);
    o.z = f2bf(ca[c + 2] * a2 + dn * cc[c + 2]);
    o.w = f2bf(ca[c + 3] * a3 + dn * cc[c + 3]);
    ((ushort4*)out)[(size_t)node * 64 + lane] = o;
}

// ---------------- BN coeffs (re-zeros stats) ----------------
__global__ void k_coeffs(float* __restrict__ sums, float* __restrict__ sumsq,
                         const float* __restrict__ g, const float* __restrict__ beta,
                         float* __restrict__ ca, float* __restrict__ cc, int n) {
    int c = blockIdx.x * blockDim.x + threadIdx.x;
    if (c >= n) return;
    float mean = sums[c] * (1.0f / MNODES);
    float var  = sumsq[c] * (1.0f / MNODES) - mean * mean;
    float a    = g[c] * rsqrtf(var + BN_EPS);
    ca[c] = a;
    cc[c] = beta[c] - a * mean;
    sums[c] = 0.f;
    sumsq[c] = 0.f;
}

// ---------------- h = relu(ca*h + cc), in place, bf16, 512 cols --------------
__global__ void k_prerelu(ushort_t* __restrict__ h, const float* __restrict__ ca,
                          const float* __restrict__ cc) {
    int i = blockIdx.x * blockDim.x + threadIdx.x;  // over M*512/4
    if (i >= MNODES * (D2 / 4)) return;
    int c = (i * 4) & (D2 - 1);
    ushort4 v = ((const ushort4*)h)[i];
    ushort4 o;
    o.x = f2bf(fmaxf(ca[c + 0] * bf2f(v.x) + cc[c + 0], 0.f));
    o.y = f2bf(fmaxf(ca[c + 1] * bf2f(v.y) + cc[c + 1], 0.f));
    o.z = f2bf(fmaxf(ca[c + 2] * bf2f(v.z) + cc[c + 2], 0.f));
    o.w = f2bf(fmaxf(ca[c + 3] * bf2f(v.w) + cc[c + 3], 0.f));
    ((ushort4*)h)[i] = o;
}

// ---------------- final: d_out = ca*h + cc (fp32) ----------------
__global__ void k_apply_out(const ushort_t* __restrict__ h, const float* __restrict__ ca,
                            const float* __restrict__ cc, float* __restrict__ out) {
    int i = blockIdx.x * blockDim.x + threadIdx.x;
    if (i >= MNODES * 64) return;
    int c = (i & 63) * 4;
    ushort4 v = ((const ushort4*)h)[i];
    float4 o;
    o.x = ca[c + 0] * bf2f(v.x) + cc[c + 0];
    o.y = ca[c + 1] * bf2f(v.y) + cc[c + 1];
    o.z = ca[c + 2] * bf2f(v.z) + cc[c + 2];
    o.w = ca[c + 3] * bf2f(v.w) + cc[c + 3];
    ((float4*)out)[i] = o;
}

// ---------------- pipelined bf16 MFMA GEMM, 128x128 tile, BK=32 --------------
// DMA staging (global_load_lds, conflict-free), double-buffered LDS (32 KB),
// raw s_barrier + fine vmcnt(4): tile t+2 loads stay in flight across barriers.
// LDS layout: row r (32 ushort = 64 B), 4 chunks of 8; slot s holds global
// chunk s ^ ((r>>2)&3)  -> fragment ds_read_b128 is 2-way max (free).
template<int DO_STATS, int RES>
__global__ __launch_bounds__(256, 4)
void k_gemm_bf(const ushort_t* __restrict__ A, const ushort_t* __restrict__ WT,
               const float* __restrict__ bias,
               const ushort_t* resid, const float* __restrict__ r_ca,
               const float* __restrict__ r_cc,
               ushort_t* out, float* __restrict__ sums, float* __restrict__ sumsq,
               int M, int K, int N) {
    __shared__ __align__(16) ushort_t As[2][128 * 32];
    __shared__ __align__(16) ushort_t Bs[2][128 * 32];
    const int tid = threadIdx.x;
    const int w = tid >> 6, lane = tid & 63;
    const int wm = w >> 1, wn = w & 1;
    const int quad = lane >> 4, l15 = lane & 15;
    const int m0 = blockIdx.y * 128, n0 = blockIdx.x * 128;

    // staging: 8 issues of 16 rows per tile (A and B each); wave w does issues
    // {w, w+4}. lane i covers row rbase+(i>>2), slot i&3.
    const ushort_t* aA[2];
    const ushort_t* aB[2];
    int aoff[2];
    #pragma unroll
    for (int j = 0; j < 2; j++) {
        int ii = j * 4 + w;
        int r = ii * 16 + (lane >> 2);
        int cg = (lane & 3) ^ ((r >> 2) & 3);
        aA[j] = A  + (size_t)(m0 + r) * K + cg * 8;
        aB[j] = WT + (size_t)(n0 + r) * K + cg * 8;
        aoff[j] = ii * 512;              // 16 rows * 32 ushort
    }

    v4f acc[4][4];
    #pragma unroll
    for (int i = 0; i < 4; i++)
        #pragma unroll
        for (int j = 0; j < 4; j++)
            acc[i][j] = (v4f){0.f, 0.f, 0.f, 0.f};

    const int nk = K >> 5;               // >= 4 for all our shapes

    // prologue: issue tiles 0 and 1; drain tile 0 only
    #pragma unroll
    for (int j = 0; j < 2; j++) {
        async16(aA[j], &As[0][aoff[j]]);
        async16(aB[j], &Bs[0][aoff[j]]);
    }
    #pragma unroll
    for (int j = 0; j < 2; j++) {
        async16(aA[j] + 32, &As[1][aoff[j]]);
        async16(aB[j] + 32, &Bs[1][aoff[j]]);
    }
    VMWAIT4();
    BARRIER();

    const int sl = quad ^ ((l15 >> 2) & 3);
    for (int t = 0; t < nk; t++) {
        const ushort_t* Ab = As[t & 1];
        const ushort_t* Bb = Bs[t & 1];
        v8bf af[4], bfr[4];
        #pragma unroll
        for (int tt = 0; tt < 4; tt++) {
            int m_l = wm * 64 + tt * 16 + l15;
            af[tt]  = *(const v8bf*)&Ab[m_l * 32 + sl * 8];
            int n_l = wn * 64 + tt * 16 + l15;
            bfr[tt] = *(const v8bf*)&Bb[n_l * 32 + sl * 8];
        }
        #pragma unroll
        for (int mt = 0; mt < 4; mt++)
            #pragma unroll
            for (int nt = 0; nt < 4; nt++)
                acc[mt][nt] = __builtin_amdgcn_mfma_f32_16x16x32_bf16(
                    af[mt], bfr[nt], acc[mt][nt], 0, 0, 0);
        if (t == nk - 1) break;
        BARRIER();                        // all waves done reading buf[t&1]
        if (t + 2 < nk) {
            int kl = (t + 2) * 32;
            #pragma unroll
            for (int j = 0; j < 2; j++) {
                async16(aA[j] + kl, &As[t & 1][aoff[j]]);
                async16(aB[j] + kl, &Bs[t & 1][aoff[j]]);
            }
            VMWAIT4();                    // drain tile t+1; t+2 stays in flight
        } else {
            VMWAIT0();                    // last prefetch: drain tile t+1
        }
        BARRIER();                        // everyone's tile t+1 DMA visible
    }

    // epilogue: bias (+ lazy-BN residual) -> bf16 store + fused column stats
    const int mlim = M - m0;
    float s_sum[4] = {0.f, 0.f, 0.f, 0.f}, s_sq[4] = {0.f, 0.f, 0.f, 0.f};
    #pragma unroll
    for (int nt = 0; nt < 4; nt++) {
        int colg = n0 + wn * 64 + nt * 16 + l15;
        float bia = bias[colg];
        float rca = 0.f, rcc = 0.f;
        if (RES) { rca = r_ca[colg]; rcc = r_cc[colg]; }
        #pragma unroll
        for (int mt = 0; mt < 4; mt++) {
            int rbase = wm * 64 + mt * 16 + quad * 4;
            #pragma unroll
            for (int r = 0; r < 4; r++) {
                int rl = rbase + r;
                if (rl < mlim) {
                    size_t idx = (size_t)(m0 + rl) * N + colg;
                    float v = acc[mt][nt][r] + bia;
                    if (RES) v += rca * bf2f(resid[idx]) + rcc;
                    out[idx] = f2bf(v);
                    if (DO_STATS) { s_sum[nt] += v; s_sq[nt] += v * v; }
                }
            }
        }
    }
    if (DO_STATS) {
        #pragma unroll
        for (int nt = 0; nt < 4; nt++) {
            float s = s_sum[nt], q = s_sq[nt];
            s += __shfl_xor(s, 16); q += __shfl_xor(q, 16);
            s += __shfl_xor(s, 32); q += __shfl_xor(q, 32);
            if (quad == 0) {
                int colg = n0 + wn * 64 + nt * 16 + l15;
                atomicAdd(&sums[colg], s);
                atomicAdd(&sumsq[colg], q);
            }
        }
    }
}

extern "C" void kernel_launch(void* const* d_in, const int* in_sizes, int n_in,
                              void* d_out, int out_size, void* d_ws, size_t ws_size,
                              hipStream_t stream) {
    const float* pre   = (const float*)d_in[0];
    const int*   ei    = (const int*)d_in[1];
    const float* W0    = (const float*)d_in[2];
    const float* b0    = (const float*)d_in[3];
    const float* W1    = (const float*)d_in[4];
    const float* b1    = (const float*)d_in[5];
    const float* g1    = (const float*)d_in[6];
    const float* beta1 = (const float*)d_in[7];
    const float* W2    = (const float*)d_in[8];
    const float* b2    = (const float*)d_in[9];
    const float* gf    = (const float*)d_in[10];
    const float* betaf = (const float*)d_in[11];

    char* p = (char*)d_ws;
    ushort_t* preb = (ushort_t*)p; p += (size_t)M_PAD * DIN * 2;
    ushort_t* ACT1 = (ushort_t*)p; p += (size_t)M_PAD * DD * 2;
    ushort_t* ACT2 = (ushort_t*)p; p += (size_t)M_PAD * DD * 2;
    ushort_t* H1   = (ushort_t*)p; p += (size_t)M_PAD * D2 * 2;
    ushort_t* W0T  = (ushort_t*)p; p += (size_t)DIN * DD * 2;
    ushort_t* W1T  = (ushort_t*)p; p += (size_t)NLAYERS * DD * D2 * 2;
    ushort_t* W2T  = (ushort_t*)p; p += (size_t)NLAYERS * D2 * DD * 2;
    float* sums1  = (float*)p; p += D2 * 4;
    float* sumsq1 = (float*)p; p += D2 * 4;
    float* ca1    = (float*)p; p += D2 * 4;
    float* cc1    = (float*)p; p += D2 * 4;
    float* sumsF  = (float*)p; p += DD * 4;
    float* sumsqF = (float*)p; p += DD * 4;
    float* caf    = (float*)p; p += DD * 4;
    float* ccf    = (float*)p; p += DD * 4;
    int* deg    = (int*)p; p += (size_t)MNODES * 4;
    int* rowptr = (int*)p; p += (size_t)(MNODES + 1) * 4;
    int* cursor = (int*)p; p += (size_t)MNODES * 4;
    int* colx   = (int*)p; p += (size_t)NEDGES * 4;
    int* bsum   = (int*)p; p += 256 * 4;

    dim3 blk(256);
    const int mb = (MNODES + 127) / 128;        // 391
    const int nsb = (MNODES + 255) / 256;       // 196

    const int prep_total = R0 + RW + 256 + 1024 + 512 + MNODES;
    k_prep_all<<<(prep_total + 255) / 256, blk, 0, stream>>>(
        pre, preb, W0, W1, W2, W0T, W1T, W2T, caf, ccf, sums1, sumsF, deg);

    k_hist<<<(NEDGES + 255) / 256, blk, 0, stream>>>(ei, deg);
    k_scan1<<<nsb, blk, 0, stream>>>(deg, rowptr, bsum, MNODES);
    k_scan2<<<1, blk, 0, stream>>>(bsum, nsb);
    k_scan3<<<nsb, blk, 0, stream>>>(deg, bsum, rowptr, cursor, MNODES);
    k_fill<<<(NEDGES + 255) / 256, blk, 0, stream>>>(ei, cursor, colx);

    // X0 = pre @ W0 + b0  -> ACT2
    k_gemm_bf<0, 0><<<dim3(DD / 128, mb), blk, 0, stream>>>(
        preb, W0T, b0, nullptr, nullptr, nullptr,
        ACT2, nullptr, nullptr, MNODES, DIN, DD);

    for (int l = 0; l < NLAYERS; l++) {
        // ACT1 = caf*(ACT2[n] + sum ACT2[src]) + (deg+1)*ccf
        k_gather<<<(MNODES + 3) / 4, blk, 0, stream>>>(rowptr, colx, ACT2, caf, ccf, ACT1);

        // H1 = ACT1 @ W1 + b1, fused column stats
        k_gemm_bf<1, 0><<<dim3(D2 / 128, mb), blk, 0, stream>>>(
            ACT1, W1T + (size_t)l * DD * D2, b1 + (size_t)l * D2,
            nullptr, nullptr, nullptr,
            H1, sums1, sumsq1, MNODES, DD, D2);
        k_coeffs<<<2, blk, 0, stream>>>(sums1, sumsq1, g1 + (size_t)l * D2,
                                        beta1 + (size_t)l * D2, ca1, cc1, D2);

        // H1 = relu(bn1(H1)) in place
        k_prerelu<<<(MNODES * (D2 / 4) + 255) / 256, blk, 0, stream>>>(H1, ca1, cc1);

        // ACT2 = H1 @ W2 + b2 + bn_prev(ACT2)  (in place; fused stats)
        k_gemm_bf<1, 1><<<dim3(DD / 128, mb), blk, 0, stream>>>(
            H1, W2T + (size_t)l * D2 * DD, b2 + (size_t)l * DD,
            ACT2, caf, ccf,
            ACT2, sumsF, sumsqF, MNODES, D2, DD);
        k_coeffs<<<1, blk, 0, stream>>>(sumsF, sumsqF, gf + (size_t)l * DD,
                                        betaf + (size_t)l * DD, caf, ccf, DD);
    }

    // d_out = caf*ACT2 + ccf  (fp32)
    k_apply_out<<<(MNODES * 64 + 255) / 256, blk, 0, stream>>>(ACT2, caf, ccf, (float*)d_out);
}